// Round 7
// baseline (149.266 us; speedup 1.0000x reference)
//
#include <hip/hip_runtime.h>

#define C_DIM 256
#define NCODE 1024
#define MARGIN 0.02f

typedef __bf16 bf16x8 __attribute__((ext_vector_type(8)));
typedef float f32x4 __attribute__((ext_vector_type(4)));

// ws layout (byte offsets)
#define WS_ENORM 0         // f32[1024]
#define WS_META  4096      // u32 rescue count
#define WS_RLIST 8192      // u32[32768]
#define WS_BP    139264    // u16[32 chunks][16384] (1 MB) pre-fragmented B'
#define WS_PB    1187840   // float2[32768][2] (b1,b2) per (row, half)
#define WS_PBI   1712128   // u32[32768][2]    i1      per (row, half)

#define GLOAD_LDS16(g, s)                                                            \
  __builtin_amdgcn_global_load_lds(                                                  \
      (const __attribute__((address_space(1))) unsigned int*)(g),                    \
      (__attribute__((address_space(3))) unsigned int*)(s), 16, 0, 0)

__device__ __forceinline__ void bf16split(float x, unsigned short& h, unsigned short& l) {
    unsigned u  = __float_as_uint(x);
    unsigned rh = (u + 0x7FFFu + ((u >> 16) & 1u)) & 0xFFFF0000u;   // RNE to bf16
    float    lf = x - __uint_as_float(rh);                          // exact
    unsigned ul = __float_as_uint(lf);
    h = (unsigned short)(rh >> 16);
    l = (unsigned short)((ul + 0x7FFFu + ((ul >> 16) & 1u)) >> 16);
}

// ---------- prep_misc: enorm (fp32 wave-reduce) + meta reset ----------
__global__ __launch_bounds__(256) void prep_misc_kernel(const float* __restrict__ emb,
                                                        float* __restrict__ enorm,
                                                        unsigned* __restrict__ meta) {
    int gid = blockIdx.x * 256 + threadIdx.x;
    if (gid == 0) meta[0] = 0u;
    int row = gid >> 6, lane = gid & 63;
    float4 v = reinterpret_cast<const float4*>(emb)[(size_t)row * 64 + lane];
    float s = v.x * v.x + v.y * v.y + v.z * v.z + v.w * v.w;
    #pragma unroll
    for (int off = 32; off; off >>= 1) s += __shfl_xor(s, off, 64);
    if (lane == 0) enorm[row] = s;
}

// ---------- prep_b: split emb -> B' in MFMA-frag order ----------
// chunk = 32 codes. frag f = side*16 + nf*8 + kc (side 0=hi,1=lo; nf=code-16-
// group; kc=k/32). Within frag: lane (lg*16+lr) holds e[nf*16+lr][kc*32+lg*8..+7].
__global__ __launch_bounds__(256) void prep_b_kernel(const float* __restrict__ emb,
                                                     unsigned short* __restrict__ bp) {
    int tid = blockIdx.x * 256 + threadIdx.x;   // 32768 = 1024 codes x 32
    int j   = tid >> 5;                         // code
    int u   = tid & 31;
    int kc  = u >> 2, lg = u & 3;
    const float* src = emb + (size_t)j * C_DIM + kc * 32 + lg * 8;
    float4 v0 = *reinterpret_cast<const float4*>(src);
    float4 v1 = *reinterpret_cast<const float4*>(src + 4);
    float vs[8] = {v0.x, v0.y, v0.z, v0.w, v1.x, v1.y, v1.z, v1.w};
    unsigned short h[8], l[8];
    #pragma unroll
    for (int k = 0; k < 8; ++k) bf16split(vs[k], h[k], l[k]);
    int chunk = j >> 5, nf = (j >> 4) & 1, lr = j & 15;
    int lane  = lg * 16 + lr;
    size_t base = (size_t)chunk * 16384 + (size_t)(nf * 8 + kc) * 512 + lane * 8;
    uint4 hp, lp;
    hp.x = (unsigned)h[0] | ((unsigned)h[1] << 16);
    hp.y = (unsigned)h[2] | ((unsigned)h[3] << 16);
    hp.z = (unsigned)h[4] | ((unsigned)h[5] << 16);
    hp.w = (unsigned)h[6] | ((unsigned)h[7] << 16);
    lp.x = (unsigned)l[0] | ((unsigned)l[1] << 16);
    lp.y = (unsigned)l[2] | ((unsigned)l[3] << 16);
    lp.z = (unsigned)l[4] | ((unsigned)l[5] << 16);
    lp.w = (unsigned)l[6] | ((unsigned)l[7] << 16);
    *reinterpret_cast<uint4*>(bp + base)             = hp;   // hi side
    *reinterpret_cast<uint4*>(bp + base + 16 * 512)  = lp;   // lo side
}

// ---------- main: 3-pass split-bf16 MFMA over a 512-code half ----------
// grid 512 = 256 M-tiles x 2 code-halves -> 2 blocks/CU, 16 waves/CU.
// Block: 128 rows x 512 codes. 8 waves = 4 row-groups x 2 code-subgroups.
// A (z hi/lo) in registers; B' chunks (32 codes) double-buffered via
// global_load_lds + counted vmcnt(4).
__global__ __launch_bounds__(512, 2) void vq_main_kernel(
    const float* __restrict__ z, const unsigned short* __restrict__ bp,
    const float* __restrict__ enorm, float2* __restrict__ pb,
    unsigned* __restrict__ pbi) {
    __shared__ alignas(16) unsigned short Bds[2][16384];   // 64 KB
    __shared__ float en_s[512];
    __shared__ float mv1[128][2], mv2[128][2];
    __shared__ unsigned mi[128][2];

    const int t    = threadIdx.x;
    const int w    = t >> 6;       // wave 0..7
    const int lane = t & 63;
    const int lr   = lane & 15, lg = lane >> 4;
    const int wm   = w >> 1;       // row-group 0..3 (32 rows each)
    const int ng   = w & 1;        // code-half within chunk (16 codes)
    const int  nh  = blockIdx.x & 1;              // code half 0/1
    const long r0  = (long)(blockIdx.x >> 1) * 128;
    const unsigned short* bph = bp + (size_t)nh * 16 * 16384;

    // stage chunk 0 (4 gload_lds per thread; frag f = round*8 + w)
    #pragma unroll
    for (int round = 0; round < 4; ++round) {
        int f = round * 8 + w;
        GLOAD_LDS16(bph + (size_t)f * 512 + lane * 8, &Bds[0][f * 512]);
    }
    if (t < 512) en_s[t] = enorm[nh * 512 + t];

    // A: load my 32 rows' z, split to bf16 hi/lo fragments (128 VGPR)
    bf16x8 ah[2][8], al[2][8];
    #pragma unroll
    for (int m = 0; m < 2; ++m) {
        const float* zr = z + (r0 + wm * 32 + m * 16 + lr) * C_DIM + lg * 8;
        #pragma unroll
        for (int kc = 0; kc < 8; ++kc) {
            float4 v0 = *reinterpret_cast<const float4*>(zr + kc * 32);
            float4 v1 = *reinterpret_cast<const float4*>(zr + kc * 32 + 4);
            float vs[8] = {v0.x, v0.y, v0.z, v0.w, v1.x, v1.y, v1.z, v1.w};
            unsigned short hv[8], lv[8];
            #pragma unroll
            for (int jj = 0; jj < 8; ++jj) bf16split(vs[jj], hv[jj], lv[jj]);
            unsigned hp[4] = {
                (unsigned)hv[0] | ((unsigned)hv[1] << 16), (unsigned)hv[2] | ((unsigned)hv[3] << 16),
                (unsigned)hv[4] | ((unsigned)hv[5] << 16), (unsigned)hv[6] | ((unsigned)hv[7] << 16)};
            unsigned lp[4] = {
                (unsigned)lv[0] | ((unsigned)lv[1] << 16), (unsigned)lv[2] | ((unsigned)lv[3] << 16),
                (unsigned)lv[4] | ((unsigned)lv[5] << 16), (unsigned)lv[6] | ((unsigned)lv[7] << 16)};
            ah[m][kc] = __builtin_bit_cast(bf16x8, *reinterpret_cast<uint4*>(hp));
            al[m][kc] = __builtin_bit_cast(bf16x8, *reinterpret_cast<uint4*>(lp));
        }
    }

    float b1[2][4], b2[2][4]; unsigned i1[2][4];
    #pragma unroll
    for (int m = 0; m < 2; ++m)
        #pragma unroll
        for (int r = 0; r < 4; ++r) { b1[m][r] = 3.4e38f; b2[m][r] = 3.4e38f; i1[m][r] = 0; }

    for (int c = 0; c < 16; ++c) {
        const int cur = c & 1;
        __syncthreads();   // everyone done reading buf[cur^1] (chunk c-1)
        if (c < 15) {
            const unsigned short* src = bph + (size_t)(c + 1) * 16384;
            #pragma unroll
            for (int round = 0; round < 4; ++round) {
                int f = round * 8 + w;
                GLOAD_LDS16(src + (size_t)f * 512 + lane * 8, &Bds[cur ^ 1][f * 512]);
            }
            asm volatile("s_waitcnt vmcnt(4)" ::: "memory");   // chunk c landed; c+1 in flight
        } else {
            asm volatile("s_waitcnt vmcnt(0)" ::: "memory");
        }
        __syncthreads();   // chunk c visible to all waves

        // 6 independent accumulator chains (hh/hl/lh x 2 m-frags)
        f32x4 hh0 = {0.f,0.f,0.f,0.f}, hh1 = {0.f,0.f,0.f,0.f};
        f32x4 hl0 = {0.f,0.f,0.f,0.f}, hl1 = {0.f,0.f,0.f,0.f};
        f32x4 lh0 = {0.f,0.f,0.f,0.f}, lh1 = {0.f,0.f,0.f,0.f};
        const unsigned short* bb = &Bds[cur][(ng * 8) * 512 + lane * 8];
        #pragma unroll
        for (int kc = 0; kc < 8; ++kc) {
            bf16x8 bh = *reinterpret_cast<const bf16x8*>(bb + kc * 512);
            bf16x8 bl = *reinterpret_cast<const bf16x8*>(bb + (16 + kc) * 512);
            hh0 = __builtin_amdgcn_mfma_f32_16x16x32_bf16(ah[0][kc], bh, hh0, 0, 0, 0);
            hh1 = __builtin_amdgcn_mfma_f32_16x16x32_bf16(ah[1][kc], bh, hh1, 0, 0, 0);
            lh0 = __builtin_amdgcn_mfma_f32_16x16x32_bf16(al[0][kc], bh, lh0, 0, 0, 0);
            lh1 = __builtin_amdgcn_mfma_f32_16x16x32_bf16(al[1][kc], bh, lh1, 0, 0, 0);
            hl0 = __builtin_amdgcn_mfma_f32_16x16x32_bf16(ah[0][kc], bl, hl0, 0, 0, 0);
            hl1 = __builtin_amdgcn_mfma_f32_16x16x32_bf16(ah[1][kc], bl, hl1, 0, 0, 0);
        }

        const float    en   = en_s[c * 32 + ng * 16 + lr];
        const unsigned code = (unsigned)(nh * 512 + c * 32 + ng * 16 + lr);  // ascends
        #pragma unroll
        for (int r = 0; r < 4; ++r) {
            float d0 = fmaf(-2.f, hh0[r] + hl0[r] + lh0[r], en);
            if (d0 < b1[0][r]) { b2[0][r] = b1[0][r]; b1[0][r] = d0; i1[0][r] = code; }
            else if (d0 < b2[0][r]) { b2[0][r] = d0; }
            float d1 = fmaf(-2.f, hh1[r] + hl1[r] + lh1[r], en);
            if (d1 < b1[1][r]) { b2[1][r] = b1[1][r]; b1[1][r] = d1; i1[1][r] = code; }
            else if (d1 < b2[1][r]) { b2[1][r] = d1; }
        }
    }

    // cross-lane (lr) top-2 merge, then cross-ng merge via LDS
    #pragma unroll
    for (int m = 0; m < 2; ++m)
        #pragma unroll
        for (int r = 0; r < 4; ++r) {
            float v1 = b1[m][r], v2 = b2[m][r]; unsigned j1 = i1[m][r];
            #pragma unroll
            for (int off = 8; off; off >>= 1) {
                float    ov1 = __shfl_xor(v1, off, 64);
                float    ov2 = __shfl_xor(v2, off, 64);
                unsigned oj1 = (unsigned)__shfl_xor((int)j1, off, 64);
                if (ov1 < v1 || (ov1 == v1 && oj1 < j1)) {
                    v2 = fminf(v1, ov2); v1 = ov1; j1 = oj1;
                } else {
                    v2 = fminf(v2, ov1);
                }
            }
            if (lr == 0) {
                int rowl = wm * 32 + m * 16 + lg * 4 + r;
                mv1[rowl][ng] = v1; mv2[rowl][ng] = v2; mi[rowl][ng] = j1;
            }
        }
    __syncthreads();
    if (t < 128) {
        float B1 = mv1[t][0], B2 = mv2[t][0]; unsigned I1 = mi[t][0];
        float o1 = mv1[t][1], o2 = mv2[t][1]; unsigned O1 = mi[t][1];
        if (o1 < B1 || (o1 == B1 && O1 < I1)) { B2 = fminf(B1, o2); B1 = o1; I1 = O1; }
        else                                  { B2 = fminf(B2, o1); }
        pb [(r0 + t) * 2 + nh] = make_float2(B1, B2);
        pbi[(r0 + t) * 2 + nh] = I1;
    }
}

// ---------- finalize+gather: merge 2 halves, idx, rescue-flag, z_q ----------
// grid n/4 blocks x 256 thr: 4 rows/block, 64 lanes/row (1 float4 each).
__global__ __launch_bounds__(256) void finalize_gather_kernel(
    const float* __restrict__ emb, const float2* __restrict__ pb,
    const unsigned* __restrict__ pbi, float* __restrict__ zq,
    float* __restrict__ idx_out, unsigned* __restrict__ meta,
    unsigned* __restrict__ rlist) {
    const long row = (long)blockIdx.x * 4 + (threadIdx.x >> 6);
    const int lane = threadIdx.x & 63;
    float2   p0 = pb [row * 2 + 0], p1 = pb [row * 2 + 1];
    unsigned j0 = pbi[row * 2 + 0], j1 = pbi[row * 2 + 1];
    // half-0 codes all < half-1 codes: strict < keeps first index
    float B1, B2; unsigned I1;
    if (p1.x < p0.x) { B1 = p1.x; I1 = j1; B2 = fminf(p0.x, p1.y); }
    else             { B1 = p0.x; I1 = j0; B2 = fminf(p0.y, p1.x); }
    if (lane == 0) {
        idx_out[row] = (float)I1;
        if (B2 - B1 <= MARGIN) rlist[atomicAdd(meta, 1u)] = (unsigned)row;
    }
    float4 v = reinterpret_cast<const float4*>(emb)[(size_t)I1 * 64 + lane];
    reinterpret_cast<float4*>(zq)[row * 64 + lane] = v;
}

// ---------- rescue: exact fp32 argmin for flagged rows; writes z_q+idx ----------
__global__ __launch_bounds__(256) void rescue_kernel(
    const float* __restrict__ z, const float* __restrict__ emb,
    const float* __restrict__ enorm, const unsigned* __restrict__ meta,
    const unsigned* __restrict__ rlist, float* __restrict__ zq,
    float* __restrict__ idx_out) {
    __shared__ float zrow[C_DIM];
    __shared__ float rd[256];
    __shared__ unsigned rix[256];
    const unsigned cnt = meta[0];
    for (unsigned li = blockIdx.x; li < cnt; li += gridDim.x) {
        unsigned row = rlist[li];
        __syncthreads();
        if (threadIdx.x < 64) {
            float4 v = reinterpret_cast<const float4*>(z)[(size_t)row * 64 + threadIdx.x];
            reinterpret_cast<float4*>(zrow)[threadIdx.x] = v;
        }
        __syncthreads();
        const int c = threadIdx.x;
        float a0 = 0.f, a1 = 0.f, a2 = 0.f, a3 = 0.f;
        const float4* zp = reinterpret_cast<const float4*>(zrow);
        const float4* e0 = reinterpret_cast<const float4*>(emb + (size_t)(c)       * C_DIM);
        const float4* e1 = reinterpret_cast<const float4*>(emb + (size_t)(c + 256) * C_DIM);
        const float4* e2 = reinterpret_cast<const float4*>(emb + (size_t)(c + 512) * C_DIM);
        const float4* e3 = reinterpret_cast<const float4*>(emb + (size_t)(c + 768) * C_DIM);
        #pragma unroll 8
        for (int k = 0; k < 64; ++k) {
            float4 z4 = zp[k];
            float4 f0 = e0[k], f1 = e1[k], f2 = e2[k], f3 = e3[k];
            a0 = fmaf(z4.x, f0.x, a0); a0 = fmaf(z4.y, f0.y, a0);
            a0 = fmaf(z4.z, f0.z, a0); a0 = fmaf(z4.w, f0.w, a0);
            a1 = fmaf(z4.x, f1.x, a1); a1 = fmaf(z4.y, f1.y, a1);
            a1 = fmaf(z4.z, f1.z, a1); a1 = fmaf(z4.w, f1.w, a1);
            a2 = fmaf(z4.x, f2.x, a2); a2 = fmaf(z4.y, f2.y, a2);
            a2 = fmaf(z4.z, f2.z, a2); a2 = fmaf(z4.w, f2.w, a2);
            a3 = fmaf(z4.x, f3.x, a3); a3 = fmaf(z4.y, f3.y, a3);
            a3 = fmaf(z4.z, f3.z, a3); a3 = fmaf(z4.w, f3.w, a3);
        }
        float d0 = fmaf(-2.f, a0, enorm[c]);
        float d1 = fmaf(-2.f, a1, enorm[c + 256]);
        float d2 = fmaf(-2.f, a2, enorm[c + 512]);
        float d3 = fmaf(-2.f, a3, enorm[c + 768]);
        float bd = d0; unsigned bi = (unsigned)c;
        if (d1 < bd) { bd = d1; bi = (unsigned)(c + 256); }
        if (d2 < bd) { bd = d2; bi = (unsigned)(c + 512); }
        if (d3 < bd) { bd = d3; bi = (unsigned)(c + 768); }
        rd[threadIdx.x] = bd; rix[threadIdx.x] = bi;
        __syncthreads();
        for (int s = 128; s; s >>= 1) {
            if (threadIdx.x < (unsigned)s) {
                float od = rd[threadIdx.x + s]; unsigned oi = rix[threadIdx.x + s];
                if (od < rd[threadIdx.x] ||
                    (od == rd[threadIdx.x] && oi < rix[threadIdx.x])) {
                    rd[threadIdx.x] = od; rix[threadIdx.x] = oi;
                }
            }
            __syncthreads();
        }
        unsigned code = rix[0];
        if (threadIdx.x < 64) {
            float4 v = reinterpret_cast<const float4*>(emb)[(size_t)code * 64 + threadIdx.x];
            reinterpret_cast<float4*>(zq)[(size_t)row * 64 + threadIdx.x] = v;
        }
        if (threadIdx.x == 0) idx_out[row] = (float)code;
    }
}

extern "C" void kernel_launch(void* const* d_in, const int* in_sizes, int n_in,
                              void* d_out, int out_size, void* d_ws, size_t ws_size,
                              hipStream_t stream) {
    const float* z   = (const float*)d_in[0];
    const float* emb = (const float*)d_in[1];
    const int n = in_sizes[0] / C_DIM;   // 32768

    float* zq      = (float*)d_out;
    float* idx_out = zq + (size_t)n * C_DIM;

    char* ws = (char*)d_ws;
    float*          enorm = (float*)(ws + WS_ENORM);
    unsigned*       meta  = (unsigned*)(ws + WS_META);
    unsigned*       rlist = (unsigned*)(ws + WS_RLIST);
    unsigned short* bp    = (unsigned short*)(ws + WS_BP);
    float2*         pb    = (float2*)(ws + WS_PB);
    unsigned*       pbi   = (unsigned*)(ws + WS_PBI);

    prep_misc_kernel<<<256, 256, 0, stream>>>(emb, enorm, meta);
    prep_b_kernel<<<128, 256, 0, stream>>>(emb, bp);
    vq_main_kernel<<<(n / 128) * 2, 512, 0, stream>>>(z, bp, enorm, pb, pbi);
    finalize_gather_kernel<<<n / 4, 256, 0, stream>>>(emb, pb, pbi, zq, idx_out,
                                                      meta, rlist);
    rescue_kernel<<<256, 256, 0, stream>>>(z, emb, enorm, meta, rlist, zq, idx_out);
}

// Round 8
// 145.460 us; speedup vs baseline: 1.0262x; 1.0262x over previous
//
#include <hip/hip_runtime.h>

#define C_DIM 256
#define NCODE 1024
#define MARGIN 0.02f

typedef __bf16 bf16x8 __attribute__((ext_vector_type(8)));
typedef float f32x4 __attribute__((ext_vector_type(4)));

// ws layout (byte offsets)
#define WS_ENORM 0         // f32[1024]
#define WS_META  4096      // u32 rescue count
#define WS_RLIST 8192      // u32[32768]
#define WS_BP    139264    // u16[32 chunks][16384] (1 MB) pre-fragmented B'
#define WS_PB    1187840   // float2[32768][2] (b1,b2) per (row, half)
#define WS_PBI   1712128   // u32[32768][2]    i1      per (row, half)

__device__ __forceinline__ void bf16split(float x, unsigned short& h, unsigned short& l) {
    unsigned u  = __float_as_uint(x);
    unsigned rh = (u + 0x7FFFu + ((u >> 16) & 1u)) & 0xFFFF0000u;   // RNE to bf16
    float    lf = x - __uint_as_float(rh);                          // exact
    unsigned ul = __float_as_uint(lf);
    h = (unsigned short)(rh >> 16);
    l = (unsigned short)((ul + 0x7FFFu + ((ul >> 16) & 1u)) >> 16);
}

// ---------- prep_misc: enorm (fp32 wave-reduce) + meta reset ----------
__global__ __launch_bounds__(256) void prep_misc_kernel(const float* __restrict__ emb,
                                                        float* __restrict__ enorm,
                                                        unsigned* __restrict__ meta) {
    int gid = blockIdx.x * 256 + threadIdx.x;
    if (gid == 0) meta[0] = 0u;
    int row = gid >> 6, lane = gid & 63;
    float4 v = reinterpret_cast<const float4*>(emb)[(size_t)row * 64 + lane];
    float s = v.x * v.x + v.y * v.y + v.z * v.z + v.w * v.w;
    #pragma unroll
    for (int off = 32; off; off >>= 1) s += __shfl_xor(s, off, 64);
    if (lane == 0) enorm[row] = s;
}

// ---------- prep_b: split emb -> B' in MFMA-frag order ----------
// chunk = 32 codes. frag f = side*16 + nf*8 + kc (side 0=hi,1=lo; nf=code-16-
// group; kc=k/32). Within frag: lane (lg*16+lr) holds e[nf*16+lr][kc*32+lg*8..+7].
__global__ __launch_bounds__(256) void prep_b_kernel(const float* __restrict__ emb,
                                                     unsigned short* __restrict__ bp) {
    int tid = blockIdx.x * 256 + threadIdx.x;   // 32768 = 1024 codes x 32
    int j   = tid >> 5;                         // code
    int u   = tid & 31;
    int kc  = u >> 2, lg = u & 3;
    const float* src = emb + (size_t)j * C_DIM + kc * 32 + lg * 8;
    float4 v0 = *reinterpret_cast<const float4*>(src);
    float4 v1 = *reinterpret_cast<const float4*>(src + 4);
    float vs[8] = {v0.x, v0.y, v0.z, v0.w, v1.x, v1.y, v1.z, v1.w};
    unsigned short h[8], l[8];
    #pragma unroll
    for (int k = 0; k < 8; ++k) bf16split(vs[k], h[k], l[k]);
    int chunk = j >> 5, nf = (j >> 4) & 1, lr = j & 15;
    int lane  = lg * 16 + lr;
    size_t base = (size_t)chunk * 16384 + (size_t)(nf * 8 + kc) * 512 + lane * 8;
    uint4 hp, lp;
    hp.x = (unsigned)h[0] | ((unsigned)h[1] << 16);
    hp.y = (unsigned)h[2] | ((unsigned)h[3] << 16);
    hp.z = (unsigned)h[4] | ((unsigned)h[5] << 16);
    hp.w = (unsigned)h[6] | ((unsigned)h[7] << 16);
    lp.x = (unsigned)l[0] | ((unsigned)l[1] << 16);
    lp.y = (unsigned)l[2] | ((unsigned)l[3] << 16);
    lp.z = (unsigned)l[4] | ((unsigned)l[5] << 16);
    lp.w = (unsigned)l[6] | ((unsigned)l[7] << 16);
    *reinterpret_cast<uint4*>(bp + base)             = hp;   // hi side
    *reinterpret_cast<uint4*>(bp + base + 16 * 512)  = lp;   // lo side
}

// ---------- main: barrier-free reg-direct 3-pass split-bf16 MFMA ----------
// grid 512 = 256 M-tiles x 2 code-halves; 256 thr (4 waves).
// Wave = 32 rows x 512 codes, fully independent: A (z hi/lo) in regs,
// B' fragments streamed global->reg (L1/L2-resident), 12 indep MFMA chains,
// double-buffered B regs, no LDS, no __syncthreads.
__global__ __launch_bounds__(256, 2) void vq_main_kernel(
    const float* __restrict__ z, const unsigned short* __restrict__ bp,
    const float* __restrict__ enorm, float2* __restrict__ pb,
    unsigned* __restrict__ pbi) {
    const int t    = threadIdx.x;
    const int w    = t >> 6;
    const int lane = t & 63;
    const int lr   = lane & 15, lg = lane >> 4;
    const int  nh  = blockIdx.x & 1;                        // code half
    const long r0  = (long)(blockIdx.x >> 1) * 128 + w * 32;
    const unsigned short* bph = bp + (size_t)nh * 16 * 16384 + lane * 8;
    const float* enh = enorm + nh * 512;

    // A: load my 32 rows' z, split to bf16 hi/lo fragments
    bf16x8 ah[2][8], al[2][8];
    #pragma unroll
    for (int m = 0; m < 2; ++m) {
        const float* zr = z + (r0 + m * 16 + lr) * C_DIM + lg * 8;
        #pragma unroll
        for (int kc = 0; kc < 8; ++kc) {
            float4 v0 = *reinterpret_cast<const float4*>(zr + kc * 32);
            float4 v1 = *reinterpret_cast<const float4*>(zr + kc * 32 + 4);
            float vs[8] = {v0.x, v0.y, v0.z, v0.w, v1.x, v1.y, v1.z, v1.w};
            unsigned short hv[8], lv[8];
            #pragma unroll
            for (int jj = 0; jj < 8; ++jj) bf16split(vs[jj], hv[jj], lv[jj]);
            unsigned hp[4] = {
                (unsigned)hv[0] | ((unsigned)hv[1] << 16), (unsigned)hv[2] | ((unsigned)hv[3] << 16),
                (unsigned)hv[4] | ((unsigned)hv[5] << 16), (unsigned)hv[6] | ((unsigned)hv[7] << 16)};
            unsigned lp[4] = {
                (unsigned)lv[0] | ((unsigned)lv[1] << 16), (unsigned)lv[2] | ((unsigned)lv[3] << 16),
                (unsigned)lv[4] | ((unsigned)lv[5] << 16), (unsigned)lv[6] | ((unsigned)lv[7] << 16)};
            ah[m][kc] = __builtin_bit_cast(bf16x8, *reinterpret_cast<uint4*>(hp));
            al[m][kc] = __builtin_bit_cast(bf16x8, *reinterpret_cast<uint4*>(lp));
        }
    }

    float b1[2][4], b2[2][4]; unsigned i1[2][4];
    #pragma unroll
    for (int m = 0; m < 2; ++m)
        #pragma unroll
        for (int r = 0; r < 4; ++r) { b1[m][r] = 3.4e38f; b2[m][r] = 3.4e38f; i1[m][r] = 0; }

    // B double-buffer registers: [buf][nf]
    bf16x8 rbh[2][2], rbl[2][2];

#define LOADB(buf, cbase, kc)                                                         \
    rbh[buf][0] = *reinterpret_cast<const bf16x8*>((cbase) + ((kc)       ) * 512);    \
    rbh[buf][1] = *reinterpret_cast<const bf16x8*>((cbase) + ( 8 + (kc)  ) * 512);    \
    rbl[buf][0] = *reinterpret_cast<const bf16x8*>((cbase) + (16 + (kc)  ) * 512);    \
    rbl[buf][1] = *reinterpret_cast<const bf16x8*>((cbase) + (24 + (kc)  ) * 512);

    LOADB(0, bph, 0);   // prologue: (chunk 0, kc 0)

    for (int c = 0; c < 16; ++c) {
        const unsigned short* cbase = bph + (size_t)c * 16384;
        const unsigned short* nbase = cbase + 16384;
        const float en0 = enh[c * 32 + lr];
        const float en1 = enh[c * 32 + 16 + lr];

        f32x4 hh[2][2], hl[2][2], lh[2][2];   // [m][nf] independent chains
        #pragma unroll
        for (int m = 0; m < 2; ++m)
            #pragma unroll
            for (int nf = 0; nf < 2; ++nf) {
                hh[m][nf] = (f32x4){0.f, 0.f, 0.f, 0.f};
                hl[m][nf] = (f32x4){0.f, 0.f, 0.f, 0.f};
                lh[m][nf] = (f32x4){0.f, 0.f, 0.f, 0.f};
            }

        #pragma unroll
        for (int kc = 0; kc < 8; ++kc) {
            const int cur = kc & 1, nxt = cur ^ 1;
            if (kc < 7) {
                LOADB(nxt, cbase, kc + 1);
            } else if (c < 15) {
                LOADB(nxt, nbase, 0);
            }
            #pragma unroll
            for (int nf = 0; nf < 2; ++nf) {
                hh[0][nf] = __builtin_amdgcn_mfma_f32_16x16x32_bf16(ah[0][kc], rbh[cur][nf], hh[0][nf], 0, 0, 0);
                hh[1][nf] = __builtin_amdgcn_mfma_f32_16x16x32_bf16(ah[1][kc], rbh[cur][nf], hh[1][nf], 0, 0, 0);
                lh[0][nf] = __builtin_amdgcn_mfma_f32_16x16x32_bf16(al[0][kc], rbh[cur][nf], lh[0][nf], 0, 0, 0);
                lh[1][nf] = __builtin_amdgcn_mfma_f32_16x16x32_bf16(al[1][kc], rbh[cur][nf], lh[1][nf], 0, 0, 0);
                hl[0][nf] = __builtin_amdgcn_mfma_f32_16x16x32_bf16(ah[0][kc], rbl[cur][nf], hl[0][nf], 0, 0, 0);
                hl[1][nf] = __builtin_amdgcn_mfma_f32_16x16x32_bf16(ah[1][kc], rbl[cur][nf], hl[1][nf], 0, 0, 0);
            }
        }

        // fold chunk into per-row top-2 (codes ascend in (c, nf) per lane)
        #pragma unroll
        for (int nf = 0; nf < 2; ++nf) {
            const float    en   = nf ? en1 : en0;
            const unsigned code = (unsigned)(nh * 512 + c * 32 + nf * 16 + lr);
            #pragma unroll
            for (int m = 0; m < 2; ++m)
                #pragma unroll
                for (int r = 0; r < 4; ++r) {
                    float d = fmaf(-2.f, hh[m][nf][r] + hl[m][nf][r] + lh[m][nf][r], en);
                    if (d < b1[m][r]) { b2[m][r] = b1[m][r]; b1[m][r] = d; i1[m][r] = code; }
                    else if (d < b2[m][r]) { b2[m][r] = d; }
                }
        }
    }
#undef LOADB

    // cross-lane (lr) top-2 merge; wave-local write of half-partials
    #pragma unroll
    for (int m = 0; m < 2; ++m)
        #pragma unroll
        for (int r = 0; r < 4; ++r) {
            float v1 = b1[m][r], v2 = b2[m][r]; unsigned j1 = i1[m][r];
            #pragma unroll
            for (int off = 8; off; off >>= 1) {
                float    ov1 = __shfl_xor(v1, off, 64);
                float    ov2 = __shfl_xor(v2, off, 64);
                unsigned oj1 = (unsigned)__shfl_xor((int)j1, off, 64);
                if (ov1 < v1 || (ov1 == v1 && oj1 < j1)) {
                    v2 = fminf(v1, ov2); v1 = ov1; j1 = oj1;
                } else {
                    v2 = fminf(v2, ov1);
                }
            }
            if (lr == 0) {
                long row = r0 + m * 16 + lg * 4 + r;
                pb [row * 2 + nh] = make_float2(v1, v2);
                pbi[row * 2 + nh] = j1;
            }
        }
}

// ---------- finalize+gather: merge 2 halves, idx, rescue-flag, z_q ----------
__global__ __launch_bounds__(256) void finalize_gather_kernel(
    const float* __restrict__ emb, const float2* __restrict__ pb,
    const unsigned* __restrict__ pbi, float* __restrict__ zq,
    float* __restrict__ idx_out, unsigned* __restrict__ meta,
    unsigned* __restrict__ rlist) {
    const long row = (long)blockIdx.x * 4 + (threadIdx.x >> 6);
    const int lane = threadIdx.x & 63;
    float2   p0 = pb [row * 2 + 0], p1 = pb [row * 2 + 1];
    unsigned j0 = pbi[row * 2 + 0], j1 = pbi[row * 2 + 1];
    // half-0 codes all < half-1 codes: strict < keeps first index
    float B1, B2; unsigned I1;
    if (p1.x < p0.x) { B1 = p1.x; I1 = j1; B2 = fminf(p0.x, p1.y); }
    else             { B1 = p0.x; I1 = j0; B2 = fminf(p0.y, p1.x); }
    if (lane == 0) {
        idx_out[row] = (float)I1;
        if (B2 - B1 <= MARGIN) rlist[atomicAdd(meta, 1u)] = (unsigned)row;
    }
    float4 v = reinterpret_cast<const float4*>(emb)[(size_t)I1 * 64 + lane];
    reinterpret_cast<float4*>(zq)[row * 64 + lane] = v;
}

// ---------- rescue: exact fp32 argmin for flagged rows; writes z_q+idx ----------
__global__ __launch_bounds__(256) void rescue_kernel(
    const float* __restrict__ z, const float* __restrict__ emb,
    const float* __restrict__ enorm, const unsigned* __restrict__ meta,
    const unsigned* __restrict__ rlist, float* __restrict__ zq,
    float* __restrict__ idx_out) {
    __shared__ float zrow[C_DIM];
    __shared__ float rd[256];
    __shared__ unsigned rix[256];
    const unsigned cnt = meta[0];
    for (unsigned li = blockIdx.x; li < cnt; li += gridDim.x) {
        unsigned row = rlist[li];
        __syncthreads();
        if (threadIdx.x < 64) {
            float4 v = reinterpret_cast<const float4*>(z)[(size_t)row * 64 + threadIdx.x];
            reinterpret_cast<float4*>(zrow)[threadIdx.x] = v;
        }
        __syncthreads();
        const int c = threadIdx.x;
        float a0 = 0.f, a1 = 0.f, a2 = 0.f, a3 = 0.f;
        const float4* zp = reinterpret_cast<const float4*>(zrow);
        const float4* e0 = reinterpret_cast<const float4*>(emb + (size_t)(c)       * C_DIM);
        const float4* e1 = reinterpret_cast<const float4*>(emb + (size_t)(c + 256) * C_DIM);
        const float4* e2 = reinterpret_cast<const float4*>(emb + (size_t)(c + 512) * C_DIM);
        const float4* e3 = reinterpret_cast<const float4*>(emb + (size_t)(c + 768) * C_DIM);
        #pragma unroll 8
        for (int k = 0; k < 64; ++k) {
            float4 z4 = zp[k];
            float4 f0 = e0[k], f1 = e1[k], f2 = e2[k], f3 = e3[k];
            a0 = fmaf(z4.x, f0.x, a0); a0 = fmaf(z4.y, f0.y, a0);
            a0 = fmaf(z4.z, f0.z, a0); a0 = fmaf(z4.w, f0.w, a0);
            a1 = fmaf(z4.x, f1.x, a1); a1 = fmaf(z4.y, f1.y, a1);
            a1 = fmaf(z4.z, f1.z, a1); a1 = fmaf(z4.w, f1.w, a1);
            a2 = fmaf(z4.x, f2.x, a2); a2 = fmaf(z4.y, f2.y, a2);
            a2 = fmaf(z4.z, f2.z, a2); a2 = fmaf(z4.w, f2.w, a2);
            a3 = fmaf(z4.x, f3.x, a3); a3 = fmaf(z4.y, f3.y, a3);
            a3 = fmaf(z4.z, f3.z, a3); a3 = fmaf(z4.w, f3.w, a3);
        }
        float d0 = fmaf(-2.f, a0, enorm[c]);
        float d1 = fmaf(-2.f, a1, enorm[c + 256]);
        float d2 = fmaf(-2.f, a2, enorm[c + 512]);
        float d3 = fmaf(-2.f, a3, enorm[c + 768]);
        float bd = d0; unsigned bi = (unsigned)c;
        if (d1 < bd) { bd = d1; bi = (unsigned)(c + 256); }
        if (d2 < bd) { bd = d2; bi = (unsigned)(c + 512); }
        if (d3 < bd) { bd = d3; bi = (unsigned)(c + 768); }
        rd[threadIdx.x] = bd; rix[threadIdx.x] = bi;
        __syncthreads();
        for (int s = 128; s; s >>= 1) {
            if (threadIdx.x < (unsigned)s) {
                float od = rd[threadIdx.x + s]; unsigned oi = rix[threadIdx.x + s];
                if (od < rd[threadIdx.x] ||
                    (od == rd[threadIdx.x] && oi < rix[threadIdx.x])) {
                    rd[threadIdx.x] = od; rix[threadIdx.x] = oi;
                }
            }
            __syncthreads();
        }
        unsigned code = rix[0];
        if (threadIdx.x < 64) {
            float4 v = reinterpret_cast<const float4*>(emb)[(size_t)code * 64 + threadIdx.x];
            reinterpret_cast<float4*>(zq)[(size_t)row * 64 + threadIdx.x] = v;
        }
        if (threadIdx.x == 0) idx_out[row] = (float)code;
    }
}

extern "C" void kernel_launch(void* const* d_in, const int* in_sizes, int n_in,
                              void* d_out, int out_size, void* d_ws, size_t ws_size,
                              hipStream_t stream) {
    const float* z   = (const float*)d_in[0];
    const float* emb = (const float*)d_in[1];
    const int n = in_sizes[0] / C_DIM;   // 32768

    float* zq      = (float*)d_out;
    float* idx_out = zq + (size_t)n * C_DIM;

    char* ws = (char*)d_ws;
    float*          enorm = (float*)(ws + WS_ENORM);
    unsigned*       meta  = (unsigned*)(ws + WS_META);
    unsigned*       rlist = (unsigned*)(ws + WS_RLIST);
    unsigned short* bp    = (unsigned short*)(ws + WS_BP);
    float2*         pb    = (float2*)(ws + WS_PB);
    unsigned*       pbi   = (unsigned*)(ws + WS_PBI);

    prep_misc_kernel<<<256, 256, 0, stream>>>(emb, enorm, meta);
    prep_b_kernel<<<128, 256, 0, stream>>>(emb, bp);
    vq_main_kernel<<<(n / 128) * 2, 256, 0, stream>>>(z, bp, enorm, pb, pbi);
    finalize_gather_kernel<<<n / 4, 256, 0, stream>>>(emb, pb, pbi, zq, idx_out,
                                                      meta, rlist);
    rescue_kernel<<<512, 256, 0, stream>>>(z, emb, enorm, meta, rlist, zq, idx_out);
}